// Round 20
// baseline (126.238 us; speedup 1.0000x reference)
//
#include <hip/hip_runtime.h>
#include <math.h>

// Problem constants: B*T = 32768 rows, C=1, V=256, K=512 codes.
#define NV 256
#define NK 512
#define TSH 4096      // shorts per 16-code tile (16 codes * 256 dims, bf16)
#define SLABR 128     // rows per block (8 x-tiles of 16)

typedef unsigned short u16;
typedef unsigned int u32;
using short8  = __attribute__((ext_vector_type(8))) short;
using floatx4 = __attribute__((ext_vector_type(4))) float;

// fp32 -> bf16 round-to-nearest-even.
__device__ __forceinline__ u16 f2bf(float f) {
    unsigned int u = __float_as_uint(f);
    u += 0x7fffu + ((u >> 16) & 1u);
    return (u16)(u >> 16);
}
__device__ __forceinline__ float bf2f(u16 h) {
    return __uint_as_float(((unsigned int)h) << 16);
}
__device__ __forceinline__ floatx4 mfma16(short8 a, short8 b, floatx4 c) {
    return __builtin_amdgcn_mfma_f32_16x16x32_bf16(a, b, c, 0, 0, 0);
}

// Kernel 0: per-code esq(+2.0 bias: distance keys provably positive), bf16
// codebook packed in MFMA order shorts[tile][kc][code][8]; zero hist.
__global__ __launch_bounds__(256) void vq_prepcvt(const float* __restrict__ emb,
                                                  float* __restrict__ esq1,
                                                  u16* __restrict__ ehws,
                                                  int* __restrict__ hist) {
    const int t = threadIdx.x;
    const int lane = t & 63;
    const int code = blockIdx.x * 4 + (t >> 6);   // one wave per code
    const int nt = code >> 4, c = code & 15;
    const float4 v = *(const float4*)(emb + (size_t)code * NV + lane * 4);
    ushort4 h;
    h.x = f2bf(v.x);
    h.y = f2bf(v.y);
    h.z = f2bf(v.z);
    h.w = f2bf(v.w);
    // dim base = lane*4 -> kchunk8 = lane>>1, j0 = (lane&1)*4
    const size_t base = (size_t)nt * TSH + (size_t)(lane >> 1) * 128 + c * 8 + (lane & 1) * 4;
    *(ushort4*)(ehws + base) = h;
    float s = v.x * v.x + v.y * v.y + v.z * v.z + v.w * v.w;
#pragma unroll
    for (int m = 1; m <= 32; m <<= 1) s += __shfl_xor(s, m, 64);
    if (lane == 0) esq1[code] = s + 2.0f;
    const int g = blockIdx.x * 256 + t;
    if (g < NK) hist[g] = 0;
}

// Kernel 1 (fused search + epilogue), R20: built to FIT the 64-VGPR budget
// hipcc pins on 1024-thread blocks (R16-R19: anything larger spills ~240
// B/thread -> the 63 MB excess WRITE). Changes vs R19:
//  (a) ONE stationary code tile per wave (16 VGPR) + two sequential
//      half-passes over the codebook; per-tau argmin reduced inline and
//      RMW-min'd into kall (no rmin_tau[8] registers). Live set ~45 VGPR.
//  (b) BOTH bf16 planes of x staged in LDS (64+64 KB); the epilogue
//      reconstructs x = hi+lo from LDS (R7-proven, err ~1e-5) instead of
//      re-reading 33.5 MB of x from HBM (R19's FETCH showed the slab
//      misses L2 by epilogue time).
// Zero in-loop barriers; swapped-operand MFMA D[code][xrow].
__global__ __launch_bounds__(1024, 1) void vq_main(
    const float* __restrict__ x,
    const float* __restrict__ emb,
    const u16* __restrict__ ehws,
    const float* __restrict__ esq1,
    int* __restrict__ hist,
    float* __restrict__ out0,
    float* __restrict__ out1,
    float* __restrict__ out2) {
    __shared__ u16 xh[8 * 16 * NV];       // 64 KB: hi plane, all 8 x-tiles
    __shared__ u16 xlo[8 * 16 * NV];      // 64 KB: lo plane (epilogue only)
    __shared__ u32 kall[8][16][16];       // 8 KB: [tau][wave][row] winners
    __shared__ u32 idx_lds[SLABR];        // 512 B: per-row winning code

    const int t = threadIdx.x;
    const int wid = t >> 6;               // wave = 0..15 (also: staged row)
    const int lane = t & 63;
    const int lr = lane & 15;             // x-row within tile (D col)
    const int lg = lane >> 4;             // k-slice group / D row-quad
    const size_t row0 = (size_t)blockIdx.x * SLABR;

    // kall init (2048 u32 = 2/thread) — merged via RMW-min in the search
    ((u32*)kall)[t] = 0xffffffffu;
    ((u32*)kall)[t + 1024] = 0xffffffffu;

    // ---- prologue: stage 8 x-tiles (hi+lo planes), 2-deep pipeline ----
    {
        float4 xa = *(const float4*)(x + (row0 + wid) * NV + lane * 4);
#pragma unroll 1
        for (int tau = 0; tau < 8; ++tau) {
            float4 xn = xa;
            if (tau < 7)
                xn = *(const float4*)(x + (row0 + (tau + 1) * 16 + wid) * NV + lane * 4);
            u16 hx = f2bf(xa.x), hy = f2bf(xa.y), hz = f2bf(xa.z), hw = f2bf(xa.w);
            u32 h0 = (u32)hx | ((u32)hy << 16);
            u32 h1 = (u32)hz | ((u32)hw << 16);
            u32 l0 = (u32)f2bf(xa.x - bf2f(hx)) | ((u32)f2bf(xa.y - bf2f(hy)) << 16);
            u32 l1 = (u32)f2bf(xa.z - bf2f(hz)) | ((u32)f2bf(xa.w - bf2f(hw)) << 16);
            int byte = tau * 8192 + wid * 512 + ((lane * 8) ^ ((wid & 7) << 4));
            *(uint2*)((char*)xh + byte)  = make_uint2(h0, h1);
            *(uint2*)((char*)xlo + byte) = make_uint2(l0, l1);
            xa = xn;
        }
    }
    __syncthreads();     // the ONLY barrier before the combine phase

    // ---- search: 2 half-passes x 8 tiles, NO in-loop synchronization ----
#pragma unroll 1
    for (int half = 0; half < 2; ++half) {
        // stationary A: this wave's tile for this half (16 codes, 16 VGPR)
        const int nt = half * 16 + wid;
        const u16* bb = ehws + (size_t)nt * TSH + lane * 8;
        short8 b[8];
#pragma unroll
        for (int ks = 0; ks < 8; ++ks) b[ks] = *(const short8*)(bb + ks * 512);
        const int cbase = nt * 16 + lg * 4;   // codes lg*4+j of this tile
        float evq[4];
#pragma unroll
        for (int j = 0; j < 4; ++j) evq[j] = esq1[cbase + j];   // esq + 2.0

#pragma unroll
        for (int tau = 0; tau < 8; ++tau) {
            floatx4 ae = {0.f,0.f,0.f,0.f}, ao = {0.f,0.f,0.f,0.f};
#pragma unroll
            for (int ks = 0; ks < 8; ++ks) {
                // x-frag: row lr, dims ks*32+lg*8.. ; same XOR swizzle as write
                int byte = tau * 8192 + lr * 512 + ((ks * 64 + lg * 16) ^ ((lr & 7) << 4));
                short8 a = *(const short8*)((const char*)xh + byte);
                // SWAPPED: codes are the A operand -> D[code][xrow]
                if (ks & 1) ao = mfma16(b[ks], a, ao);
                else        ae = mfma16(b[ks], a, ae);
            }
            u32 k = 0xffffffffu;
#pragma unroll
            for (int j = 0; j < 4; ++j) {
                // d+2 = (esq+2) - 2*cross > 0 -> raw float bits are monotone
                float d = fmaf(-2.0f, ae[j] + ao[j], evq[j]);
                k = min(k, (__float_as_uint(d) & 0xfffffe00u) | (u32)(cbase + j));
            }
            // inline cross-lg reduce (2 shuffles) + RMW-min into this wave's slot
            k = min(k, (u32)__shfl_xor((int)k, 16, 64));
            k = min(k, (u32)__shfl_xor((int)k, 32, 64));
            if (lane < 16) kall[tau][wid][lane] = min(kall[tau][wid][lane], k);
        }
    }
    __syncthreads();

    // ---- final combine: min across the 16 waves -> idx_lds + hist ----
    if (t < SLABR) {
        u32 v = 0xffffffffu;
#pragma unroll
        for (int w = 0; w < 16; ++w) v = min(v, kall[t >> 4][w][t & 15]);
        const int idx = (int)(v & 511u);
        idx_lds[t] = (u32)idx;
        atomicAdd(&hist[idx], 1);       // device-scope by default
    }
    __syncthreads();

    // ---- fused epilogue: x' = hi+lo from LDS (no HBM x re-read) ----
    const size_t rb = row0 + (size_t)wid * 8;
#pragma unroll 1
    for (int batch = 0; batch < 2; ++batch) {
        const int r0 = batch * 4;
        int idx4[4];
        float4 xv[4], ev[4];
#pragma unroll
        for (int rr = 0; rr < 4; ++rr) {
            const int rloc = wid * 8 + r0 + rr;       // slab row 0..127
            idx4[rr] = (int)idx_lds[rloc];
            int byte = (rloc >> 4) * 8192 + (rloc & 15) * 512 +
                       ((lane * 8) ^ ((rloc & 7) << 4));
            uint2 h2 = *(const uint2*)((const char*)xh + byte);
            uint2 l2 = *(const uint2*)((const char*)xlo + byte);
            xv[rr].x = bf2f((u16)(h2.x & 0xffffu)) + bf2f((u16)(l2.x & 0xffffu));
            xv[rr].y = bf2f((u16)(h2.x >> 16))     + bf2f((u16)(l2.x >> 16));
            xv[rr].z = bf2f((u16)(h2.y & 0xffffu)) + bf2f((u16)(l2.y & 0xffffu));
            xv[rr].w = bf2f((u16)(h2.y >> 16))     + bf2f((u16)(l2.y >> 16));
            ev[rr] = *(const float4*)(emb + (size_t)idx4[rr] * NV + lane * 4);
        }
        float s[4];
#pragma unroll
        for (int rr = 0; rr < 4; ++rr) {
            const size_t row = rb + r0 + rr;
            float4 o;
            o.x = (ev[rr].x - xv[rr].x) + xv[rr].x;
            o.y = (ev[rr].y - xv[rr].y) + xv[rr].y;
            o.z = (ev[rr].z - xv[rr].z) + xv[rr].z;
            o.w = (ev[rr].w - xv[rr].w) + xv[rr].w;
            *(float4*)(out0 + row * NV + lane * 4) = o;
            float d0 = xv[rr].x - ev[rr].x, d1 = xv[rr].y - ev[rr].y;
            float d2 = xv[rr].z - ev[rr].z, d3 = xv[rr].w - ev[rr].w;
            s[rr] = d0 * d0 + d1 * d1 + d2 * d2 + d3 * d3;
        }
#pragma unroll
        for (int rr = 0; rr < 4; ++rr) {
#pragma unroll
            for (int m = 1; m <= 32; m <<= 1) s[rr] += __shfl_xor(s[rr], m, 64);
        }
        if (lane == 0) {
#pragma unroll
            for (int rr = 0; rr < 4; ++rr) {
                out1[rb + r0 + rr] = s[rr];
                out2[rb + r0 + rr] = s[rr];
            }
        }
    }
}

// Kernel 2: entropy of code-usage histogram (1 block; plain loads see the
// prior kernel's device-scope atomics — proven pattern).
__global__ __launch_bounds__(256) void vq_entropy(const int* __restrict__ hist,
                                                  float* __restrict__ out_ent,
                                                  int n_rows) {
    __shared__ float sdata[256];
    int t = threadIdx.x;
    float local = 0.0f;
    float invn = 1.0f / (float)n_rows;
    for (int k = t; k < NK; k += 256) {
        int h = hist[k];
        if (h > 0) {
            float p = (float)h * invn;
            local += p * logf(p);
        }
    }
    sdata[t] = local;
    __syncthreads();
    for (int s = 128; s >= 1; s >>= 1) {
        if (t < s) sdata[t] += sdata[t + s];
        __syncthreads();
    }
    if (t == 0) *out_ent = -sdata[0];
}

extern "C" void kernel_launch(void* const* d_in, const int* in_sizes, int n_in,
                              void* d_out, int out_size, void* d_ws, size_t ws_size,
                              hipStream_t stream) {
    const float* x   = (const float*)d_in[0];   // (B,T,1,256) fp32
    const float* emb = (const float*)d_in[1];   // (1,512,256) fp32

    const int n_rows = in_sizes[0] / NV;        // 32768

    float* out0 = (float*)d_out;
    float* out1 = out0 + (size_t)n_rows * NV;
    float* out2 = out1 + n_rows;
    float* ent  = out2 + n_rows;

    // ws: esq+2 (2KB) | hist (2KB) | pad | bf16 codebook (256KB)
    float* esq1  = (float*)d_ws;
    int* hist    = (int*)(esq1 + NK);
    u16* ehws    = (u16*)(hist + NK + 4);

    vq_prepcvt<<<NK / 4, 256, 0, stream>>>(emb, esq1, ehws, hist);
    vq_main<<<n_rows / SLABR, 1024, 0, stream>>>(x, emb, ehws, esq1, hist,
                                                 out0, out1, out2);
    vq_entropy<<<1, 256, 0, stream>>>(hist, ent, n_rows);
}